// Round 8
// baseline (509.846 us; speedup 1.0000x reference)
//
#include <hip/hip_runtime.h>
#include <hip/hip_bf16.h>

#define N_PTS 16384
#define TEMP_F 0.05f
#define RCUT 0.8f

typedef __attribute__((ext_vector_type(8))) short bf16x8;
typedef __attribute__((ext_vector_type(4))) float f32x4;

__device__ __forceinline__ float selu_f(float x) {
    const float scale = 1.0507009873554805f;
    const float alpha = 1.6732632423543772f;
    return x > 0.f ? scale * x : scale * alpha * (__expf(x) - 1.f);
}

__device__ __forceinline__ float fast_sqrtf(float x) {
#if __has_builtin(__builtin_amdgcn_sqrtf)
    return __builtin_amdgcn_sqrtf(x);
#else
    return sqrtf(x);
#endif
}

__device__ __forceinline__ float fast_exp2f(float x) {
#if __has_builtin(__builtin_amdgcn_exp2f)
    return __builtin_amdgcn_exp2f(x);
#else
    return exp2f(x);
#endif
}

__device__ __forceinline__ float fast_log2f(float x) {
#if __has_builtin(__builtin_amdgcn_logf)
    return __builtin_amdgcn_logf(x);
#else
    return log2f(x);
#endif
}

__device__ __forceinline__ f32x4 mfma_bf16(bf16x8 a, bf16x8 b, f32x4 c) {
    return __builtin_amdgcn_mfma_f32_16x16x32_bf16(a, b, c, 0, 0, 0);
}

__device__ __forceinline__ void split_bf16(float v, unsigned short& hi, unsigned short& lo) {
    unsigned u = __float_as_uint(v);
    hi = (unsigned short)(u >> 16);
    float ah = __uint_as_float(u & 0xFFFF0000u);
    lo = (unsigned short)(__float_as_uint(v - ah) >> 16);
}

// 32x32 cell grid over [-6.4, 6.4], h = 0.4. Clamped (clamping only affects
// sort locality, never correctness: bboxes use true coords).
__device__ __forceinline__ int cellOf(float x, float y) {
    int cx = (int)floorf((x + 6.4f) * 2.5f);
    int cy = (int)floorf((y + 6.4f) * 2.5f);
    cx = min(31, max(0, cx));
    cy = min(31, max(0, cy));
    return cy * 32 + cx;
}

// ---------------------------------------------------------------------------
// pack_kernel (unchanged): weight pre-pack into per-lane MFMA B-fragment order
// ---------------------------------------------------------------------------
__global__ __launch_bounds__(256) void pack_kernel(
    const float* __restrict__ W1, const float* __restrict__ W2,
    const float* __restrict__ W3, const float* __restrict__ W4,
    unsigned short* __restrict__ pk)
{
    int idx = blockIdx.x * 256 + threadIdx.x;   // 0..25599
    if (idx >= 25600) return;
    const float* src;
    unsigned short *dh, *dl;
    int nt, kc, l, KC;
    if (idx < 1024) {                            // W1: K=32, KC=1
        src = W1; dh = pk; dl = pk + 8192; KC = 1;
        nt = idx >> 6; kc = 0; l = idx & 63;
    } else {                                     // W2..W4: K=256, KC=8
        int t2 = idx - 1024;
        int ly = t2 >> 13;
        int r2 = t2 & 8191;
        src = (ly == 0) ? W2 : (ly == 1) ? W3 : W4;
        dh = pk + 16384 + ly * 131072;
        dl = dh + 65536;
        KC = 8;
        nt = r2 >> 9; kc = (r2 >> 6) & 7; l = r2 & 63;
    }
    int lr = l & 15, lq = l >> 4;
    int n = nt * 16 + lr;
    bf16x8 hv, lv;
    #pragma unroll
    for (int e = 0; e < 8; e++) {
        int k = kc * 32 + lq * 8 + e;
        float v = src[k * 256 + n];
        unsigned short hb, lb;
        split_bf16(v, hb, lb);
        hv[e] = (short)hb; lv[e] = (short)lb;
    }
    int base = ((nt * KC + kc) * 64 + l) * 8;
    *(bf16x8*)(dh + base) = hv;
    *(bf16x8*)(dl + base) = lv;
}

// ---------------------------------------------------------------------------
// mlp_mfma_kernel v5 (unchanged from R7): split-bf16 MFMA MLP, kc+nt rotated.
// Measured matrix content ~8us (R5 MfmaUtil arithmetic).
// ---------------------------------------------------------------------------
__global__ __launch_bounds__(512) void mlp_mfma_kernel(
    const float* __restrict__ z,
    const unsigned short* __restrict__ pk,
    const float* __restrict__ b1, const float* __restrict__ b2,
    const float* __restrict__ b3, const float* __restrict__ b4,
    const float* __restrict__ W5, const float* __restrict__ b5,
    float* __restrict__ gen)
{
    __shared__ __align__(16) unsigned short Hh[32 * 256];
    __shared__ __align__(16) unsigned short Hl[32 * 256];

    const int t  = threadIdx.x;
    const int l  = t & 63;
    const int wv = t >> 6;
    const int lr = l & 15;
    const int lq = l >> 4;
    const int row0 = blockIdx.x * 32;
    const int bro  = blockIdx.x & 7;
    const int wp   = (wv + (blockIdx.x >> 3)) & 7;

    f32x4 acc[2][2];

    {
        bf16x8 ah[2], al[2];
        #pragma unroll
        for (int m = 0; m < 2; m++) {
            const float* zp = z + (row0 + m * 16 + lr) * 32 + lq * 8;
            f32x4 z0 = *(const f32x4*)(zp);
            f32x4 z1 = *(const f32x4*)(zp + 4);
            #pragma unroll
            for (int e = 0; e < 8; e++) {
                float v = (e < 4) ? z0[e] : z1[e - 4];
                unsigned short hb, lb;
                split_bf16(v, hb, lb);
                ah[m][e] = (short)hb; al[m][e] = (short)lb;
            }
        }
        #pragma unroll
        for (int n2 = 0; n2 < 2; n2++) {
            float bv = b1[wp * 32 + n2 * 16 + lr];
            #pragma unroll
            for (int m = 0; m < 2; m++) acc[m][n2] = (f32x4){bv, bv, bv, bv};
        }
        const bf16x8* B1h = (const bf16x8*)(pk);
        const bf16x8* B1l = (const bf16x8*)(pk + 8192);
        #pragma unroll
        for (int n2 = 0; n2 < 2; n2++) {
            int nt = wp * 2 + n2;
            bf16x8 bh = B1h[nt * 64 + l];
            bf16x8 bl = B1l[nt * 64 + l];
            #pragma unroll
            for (int m = 0; m < 2; m++) {
                acc[m][n2] = mfma_bf16(ah[m], bh, acc[m][n2]);
                acc[m][n2] = mfma_bf16(ah[m], bl, acc[m][n2]);
                acc[m][n2] = mfma_bf16(al[m], bh, acc[m][n2]);
            }
        }
        #pragma unroll
        for (int m = 0; m < 2; m++) {
            #pragma unroll
            for (int n2 = 0; n2 < 2; n2++) {
                #pragma unroll
                for (int r = 0; r < 4; r++) {
                    float v = selu_f(acc[m][n2][r]);
                    int rowo = m * 16 + lq * 4 + r;
                    int n = wp * 32 + n2 * 16 + lr;
                    int o = (2 * n) ^ ((rowo & 7) << 4);
                    unsigned short hb, lb;
                    split_bf16(v, hb, lb);
                    Hh[rowo * 256 + (o >> 1)] = hb;
                    Hl[rowo * 256 + (o >> 1)] = lb;
                }
            }
        }
    }
    __syncthreads();

    #pragma unroll 1
    for (int ly = 0; ly < 3; ly++) {
        const unsigned short* wbase = pk + 16384 + ly * 131072;
        const bf16x8* Bh = (const bf16x8*)(wbase);
        const bf16x8* Bl = (const bf16x8*)(wbase + 65536);
        const float* bb = (ly == 0) ? b2 : (ly == 1) ? b3 : b4;
        #pragma unroll
        for (int n2 = 0; n2 < 2; n2++) {
            float bv = bb[wp * 32 + n2 * 16 + lr];
            #pragma unroll
            for (int m = 0; m < 2; m++) acc[m][n2] = (f32x4){bv, bv, bv, bv};
        }
        #pragma unroll 4
        for (int kci = 0; kci < 8; kci++) {
            int kc = (kci + bro) & 7;
            bf16x8 ah[2], al[2];
            #pragma unroll
            for (int m = 0; m < 2; m++) {
                int arow = m * 16 + lr;
                int o = (kc * 64 + lq * 16) ^ ((arow & 7) << 4);
                ah[m] = *(const bf16x8*)(Hh + arow * 256 + (o >> 1));
                al[m] = *(const bf16x8*)(Hl + arow * 256 + (o >> 1));
            }
            #pragma unroll
            for (int n2 = 0; n2 < 2; n2++) {
                int nt = wp * 2 + n2;
                bf16x8 bh = Bh[(nt * 8 + kc) * 64 + l];
                bf16x8 bl = Bl[(nt * 8 + kc) * 64 + l];
                #pragma unroll
                for (int m = 0; m < 2; m++) {
                    acc[m][n2] = mfma_bf16(ah[m], bh, acc[m][n2]);
                    acc[m][n2] = mfma_bf16(ah[m], bl, acc[m][n2]);
                    acc[m][n2] = mfma_bf16(al[m], bh, acc[m][n2]);
                }
            }
        }
        __syncthreads();
        #pragma unroll
        for (int m = 0; m < 2; m++) {
            #pragma unroll
            for (int n2 = 0; n2 < 2; n2++) {
                #pragma unroll
                for (int r = 0; r < 4; r++) {
                    float v = selu_f(acc[m][n2][r]);
                    int rowo = m * 16 + lq * 4 + r;
                    int n = wp * 32 + n2 * 16 + lr;
                    int o = (2 * n) ^ ((rowo & 7) << 4);
                    unsigned short hb, lb;
                    split_bf16(v, hb, lb);
                    Hh[rowo * 256 + (o >> 1)] = hb;
                    Hl[rowo * 256 + (o >> 1)] = lb;
                }
            }
        }
        __syncthreads();
    }

    if (t < 64) {
        int row = t & 31;
        int d = t >> 5;
        float sum = b5[d];
        #pragma unroll 4
        for (int k = 0; k < 256; k += 8) {
            int o = (2 * k) ^ ((row & 7) << 4);
            bf16x8 hh = *(const bf16x8*)(Hh + row * 256 + (o >> 1));
            bf16x8 ll = *(const bf16x8*)(Hl + row * 256 + (o >> 1));
            #pragma unroll
            for (int e = 0; e < 8; e++) {
                float hv = __uint_as_float(((unsigned)(unsigned short)hh[e]) << 16)
                         + __uint_as_float(((unsigned)(unsigned short)ll[e]) << 16);
                sum = fmaf(hv, W5[(k + e) * 2 + d], sum);
            }
        }
        gen[(row0 + row) * 2 + d] = sum;
    }
}

// ---------------------------------------------------------------------------
// Fallback fp32 MLP — used only if workspace too small for packed weights.
// ---------------------------------------------------------------------------
__global__ __launch_bounds__(1024) void mlp_kernel(
    const float* __restrict__ z,
    const float* __restrict__ W1, const float* __restrict__ b1,
    const float* __restrict__ W2, const float* __restrict__ b2,
    const float* __restrict__ W3, const float* __restrict__ b3,
    const float* __restrict__ W4, const float* __restrict__ b4,
    const float* __restrict__ W5, const float* __restrict__ b5,
    float* __restrict__ gen)
{
    __shared__ float h[256 * 64];

    const int t = threadIdx.x;
    const int r = t & 63;
    const int w = __builtin_amdgcn_readfirstlane(t >> 6);
    const int c0 = w * 16;
    const int row0 = blockIdx.x * 64;

    #pragma unroll
    for (int e = 0; e < 2; e++) {
        int f  = t + e * 1024;
        int rz = f >> 5;
        int kz = f & 31;
        h[kz * 64 + rz] = z[(row0 + rz) * 32 + kz];
    }
    __syncthreads();

    float acc[16];

    #pragma unroll
    for (int j = 0; j < 16; j++) acc[j] = b1[c0 + j];
    #pragma unroll 8
    for (int k = 0; k < 32; k++) {
        float hv = h[k * 64 + r];
        const float* Wr = W1 + k * 256 + c0;
        #pragma unroll
        for (int j = 0; j < 16; j++) acc[j] = fmaf(hv, Wr[j], acc[j]);
    }
    __syncthreads();
    #pragma unroll
    for (int j = 0; j < 16; j++) h[(c0 + j) * 64 + r] = selu_f(acc[j]);
    __syncthreads();

    for (int layer = 0; layer < 3; layer++) {
        const float* W = (layer == 0) ? W2 : (layer == 1) ? W3 : W4;
        const float* b = (layer == 0) ? b2 : (layer == 1) ? b3 : b4;
        #pragma unroll
        for (int j = 0; j < 16; j++) acc[j] = b[c0 + j];
        #pragma unroll 4
        for (int k = 0; k < 256; k++) {
            float hv = h[k * 64 + r];
            const float* Wr = W + k * 256 + c0;
            #pragma unroll
            for (int j = 0; j < 16; j++) acc[j] = fmaf(hv, Wr[j], acc[j]);
        }
        __syncthreads();
        #pragma unroll
        for (int j = 0; j < 16; j++) h[(c0 + j) * 64 + r] = selu_f(acc[j]);
        __syncthreads();
    }

    float p0 = 0.f, p1 = 0.f;
    #pragma unroll
    for (int kk = 0; kk < 16; kk++) {
        int k = c0 + kk;
        float hv = h[k * 64 + r];
        p0 = fmaf(hv, W5[k * 2 + 0], p0);
        p1 = fmaf(hv, W5[k * 2 + 1], p1);
    }
    __syncthreads();
    h[(0 * 16 + w) * 64 + r] = p0;
    h[(1 * 16 + w) * 64 + r] = p1;
    __syncthreads();
    if (t < 128) {
        int d  = t >> 6;
        int rr = t & 63;
        float sum = b5[d];
        #pragma unroll
        for (int ss = 0; ss < 16; ss++) sum += h[(d * 16 + ss) * 64 + rr];
        gen[(row0 + rr) * 2 + d] = sum;
    }
}

// ===========================================================================
// Spatial-sort prep kernels (counting sort by cell, then per-subtile bboxes).
// Subtile = 64 consecutive sorted points; 256 subtiles/side.
// ===========================================================================
__global__ __launch_bounds__(512) void zero_kernel(int* __restrict__ cnt) {
    int t = blockIdx.x * 512 + threadIdx.x;
    if (t < 2048) cnt[t] = 0;
}

__global__ __launch_bounds__(512) void hist_kernel(
    const float* __restrict__ pos, const float* __restrict__ gen,
    int* __restrict__ cnt)
{
    int idx = blockIdx.x * 512 + threadIdx.x;   // 0..32767
    int side = idx >> 14, i = idx & 16383;
    const float* src = side ? gen : pos;
    int cell = cellOf(src[2 * i], src[2 * i + 1]);
    atomicAdd(cnt + side * 1024 + cell, 1);
}

__global__ __launch_bounds__(1024) void scan_kernel(
    const int* __restrict__ cnt, int* __restrict__ cursor)
{
    __shared__ int buf[1024];
    int t = threadIdx.x;
    const int* c = cnt + blockIdx.x * 1024;
    int own = c[t];
    buf[t] = own;
    __syncthreads();
    for (int off = 1; off < 1024; off <<= 1) {
        int u = (t >= off) ? buf[t - off] : 0;
        __syncthreads();
        buf[t] += u;
        __syncthreads();
    }
    cursor[blockIdx.x * 1024 + t] = buf[t] - own;   // exclusive prefix
}

__global__ __launch_bounds__(512) void scatter_kernel(
    const float* __restrict__ pos, const float* __restrict__ gen,
    int* __restrict__ cursor,
    float2* __restrict__ posS, float2* __restrict__ genS,
    int* __restrict__ genOrig)
{
    int idx = blockIdx.x * 512 + threadIdx.x;   // 0..32767
    int side = idx >> 14, i = idx & 16383;
    const float* src = side ? gen : pos;
    float x = src[2 * i], y = src[2 * i + 1];
    int cell = cellOf(x, y);
    int p = atomicAdd(cursor + side * 1024 + cell, 1);
    if (side) { genS[p] = make_float2(x, y); genOrig[p] = i; }
    else      { posS[p] = make_float2(x, y); }
}

__global__ __launch_bounds__(256) void bbox_kernel(
    const float2* __restrict__ posS, const float2* __restrict__ genS,
    float4* __restrict__ posB, float4* __restrict__ genB)
{
    const float2* src = blockIdx.x ? genS : posS;
    float4* dst = blockIdx.x ? genB : posB;
    int st = threadIdx.x;   // 0..255
    float x0 = 1e30f, y0 = 1e30f, x1 = -1e30f, y1 = -1e30f;
    for (int e = 0; e < 64; e++) {
        float2 p = src[st * 64 + e];
        x0 = fminf(x0, p.x); x1 = fmaxf(x1, p.x);
        y0 = fminf(y0, p.y); y1 = fmaxf(y1, p.y);
    }
    dst[st] = make_float4(x0, y0, x1, y1);
}

// ---------------------------------------------------------------------------
// energy_binned: culled softmin-distance energy on cell-sorted data.
// Block = 16 consecutive SORTED gen queries x 32 lanes. Block-uniform subtile
// skip: keep subtile iff mindist(qbbox, stbbox) <= dmin_ub + RCUT, where
// dmin_ub = min_st maxdist(qbbox, stbbox) >= every query's true dmin
// (so no point within dmin+RCUT of any query is ever dropped; dropped-term
// bound: N*2^(-28.85*RCUT) = 2e-3 relative worst-case -> <=9e-5 energy err).
// The argmin subtile is always kept -> sums never empty. Self term excluded
// via sorted index (query i_s == candidate j_s). Ballot-based compaction
// (deterministic). Per-pair math identical to the exact kernel.
// ---------------------------------------------------------------------------
__global__ __launch_bounds__(512) void energy_binned(
    const float2* __restrict__ posS, const float2* __restrict__ genS,
    const int* __restrict__ genOrig,
    const float4* __restrict__ posB, const float4* __restrict__ genB,
    float* __restrict__ out)
{
    __shared__ float qb[4];          // query bbox x0,y0,x1,y1
    __shared__ float wmin[8];
    __shared__ float dub2s[2];
    __shared__ int   wcnt[8], wbase[8], nPG[2];
    __shared__ unsigned short listP[256], listG[256];

    const int t  = threadIdx.x;
    const int b  = blockIdx.x;
    const int s  = t & 31;
    const int rl = t >> 5;
    const int i_s = b * 16 + rl;     // sorted query index

    const float2 q = genS[i_s];

    if (t == 0) {
        float x0 = 1e30f, y0 = 1e30f, x1 = -1e30f, y1 = -1e30f;
        for (int r = 0; r < 16; r++) {
            float2 p = genS[b * 16 + r];
            x0 = fminf(x0, p.x); x1 = fmaxf(x1, p.x);
            y0 = fminf(y0, p.y); y1 = fmaxf(y1, p.y);
        }
        qb[0] = x0; qb[1] = y0; qb[2] = x1; qb[3] = y1;
    }
    __syncthreads();
    const float qx0 = qb[0], qy0 = qb[1], qx1 = qb[2], qy1 = qb[3];

    // phase A: one bbox test per thread (t<256: pos subtile, else gen)
    const int stl  = t & 255;
    const int side = t >> 8;
    float4 bb = side ? genB[stl] : posB[stl];
    float dxo = fmaxf(fmaxf(bb.x - qx1, qx0 - bb.z), 0.f);
    float dyo = fmaxf(fmaxf(bb.y - qy1, qy0 - bb.w), 0.f);
    float md2 = dxo * dxo + dyo * dyo;                 // mindist^2
    float mxx = fmaxf(bb.z - qx0, qx1 - bb.x);
    float mxy = fmaxf(bb.w - qy0, qy1 - bb.y);
    float Md2 = mxx * mxx + mxy * mxy;                 // maxdist^2
    {
        float w = Md2;
        #pragma unroll
        for (int m = 1; m < 64; m <<= 1) w = fminf(w, __shfl_xor(w, m));
        if ((t & 63) == 0) wmin[t >> 6] = w;
    }
    __syncthreads();
    if (t == 0) {
        dub2s[0] = fminf(fminf(wmin[0], wmin[1]), fminf(wmin[2], wmin[3]));
        dub2s[1] = fminf(fminf(wmin[4], wmin[5]), fminf(wmin[6], wmin[7]));
    }
    __syncthreads();
    float thr = fast_sqrtf(dub2s[side]) + RCUT;
    bool keep = md2 <= thr * thr;
    unsigned long long mk = __ballot(keep);
    int wv = t >> 6;
    if ((t & 63) == 0) wcnt[wv] = __popcll(mk);
    __syncthreads();
    if (t == 0) {
        int a = 0;
        for (int w = 0; w < 4; w++) { wbase[w] = a; a += wcnt[w]; }
        nPG[0] = a; a = 0;
        for (int w = 4; w < 8; w++) { wbase[w] = a; a += wcnt[w]; }
        nPG[1] = a;
    }
    __syncthreads();
    if (keep) {
        int p = wbase[wv] + __popcll(mk & ((1ull << (t & 63)) - 1ull));
        if (side == 0) listP[p] = (unsigned short)stl;
        else           listG[p] = (unsigned short)stl;
    }
    __syncthreads();
    const int nP = nPG[0], nG = nPG[1];

    const float cL2 = 28.853900817779268f;   // 1/(T*ln2)
    const float Tl2 = 0.034657359027997264f; // T*ln2
    const float cB  = 57.707801635558536f;   // cL2 * 2.0

    const float4* posS4 = (const float4*)posS;
    const float4* genS4 = (const float4*)genS;

    float sump = 0.f, sumn = 0.f;

    for (int idx = 0; idx < nP; idx++) {
        int st = listP[idx];
        float4 pp = posS4[st * 32 + s];
        float dx = q.x - pp.x, dy = q.y - pp.y;
        float d  = fast_sqrtf(fmaf(dx, dx, dy * dy));
        sump += fast_exp2f(fmaf(-cL2, d, cB));
        dx = q.x - pp.z; dy = q.y - pp.w;
        d  = fast_sqrtf(fmaf(dx, dx, dy * dy));
        sump += fast_exp2f(fmaf(-cL2, d, cB));
    }
    for (int idx = 0; idx < nG; idx++) {
        int st = listG[idx];
        float4 gg = genS4[st * 32 + s];
        int j0 = st * 64 + 2 * s;
        float dx = q.x - gg.x, dy = q.y - gg.y;
        float d  = fast_sqrtf(fmaf(dx, dx, dy * dy));
        float e0 = fast_exp2f(fmaf(-cL2, d, cB));
        sumn += (j0 == i_s) ? 0.f : e0;
        dx = q.x - gg.z; dy = q.y - gg.w;
        d  = fast_sqrtf(fmaf(dx, dx, dy * dy));
        float e1 = fast_exp2f(fmaf(-cL2, d, cB));
        sumn += (j0 + 1 == i_s) ? 0.f : e1;
    }

    #pragma unroll
    for (int m = 1; m < 32; m <<= 1) {
        sump += __shfl_xor(sump, m, 32);
        sumn += __shfl_xor(sumn, m, 32);
    }
    if (s == 0) {
        out[genOrig[i_s]] = Tl2 * (fast_log2f(sumn) - fast_log2f(sump));
    }
}

// ---------------------------------------------------------------------------
// Exact energy kernel (fallback if workspace too small for sort buffers).
// ---------------------------------------------------------------------------
__global__ __launch_bounds__(512) void energy_kernel(
    const float* __restrict__ gen,
    const float* __restrict__ pos,
    float* __restrict__ out)
{
    __shared__ float4 sp[512];
    __shared__ float4 sg[512];

    const int t  = threadIdx.x;
    const int s  = t & 31;
    const int rl = t >> 5;
    const int i  = blockIdx.x * 16 + rl;
    const int diagBase = ((blockIdx.x * 16) >> 10) << 10;

    const float2 q = ((const float2*)gen)[i];

    const float cL2 = 28.853900817779268f;
    const float Tl2 = 0.034657359027997264f;
    const float cB  = 57.707801635558536f;

    float p0 = 0.f, p1 = 0.f, n0 = 0.f, n1 = 0.f;

    for (int base = 0; base < N_PTS; base += 1024) {
        __syncthreads();
        sp[t] = ((const float4*)pos)[base / 2 + t];
        sg[t] = ((const float4*)gen)[base / 2 + t];
        __syncthreads();
        if (base == diagBase) {
            #pragma unroll 4
            for (int u = 0; u < 16; u++) {
                int j = base + 2 * (s + 32 * u);
                float4 pp = sp[s + 32 * u];
                float4 gg = sg[s + 32 * u];
                float dx = q.x - pp.x, dy = q.y - pp.y;
                float d  = fast_sqrtf(fmaf(dx, dx, dy * dy));
                p0 += fast_exp2f(fmaf(-cL2, d, cB));
                dx = q.x - pp.z; dy = q.y - pp.w;
                d  = fast_sqrtf(fmaf(dx, dx, dy * dy));
                p1 += fast_exp2f(fmaf(-cL2, d, cB));
                dx = q.x - gg.x; dy = q.y - gg.y;
                d  = fast_sqrtf(fmaf(dx, dx, dy * dy));
                float e0 = fast_exp2f(fmaf(-cL2, d, cB));
                n0 += (j == i) ? 0.f : e0;
                dx = q.x - gg.z; dy = q.y - gg.w;
                d  = fast_sqrtf(fmaf(dx, dx, dy * dy));
                float e1 = fast_exp2f(fmaf(-cL2, d, cB));
                n1 += (j + 1 == i) ? 0.f : e1;
            }
        } else {
            #pragma unroll 4
            for (int u = 0; u < 16; u++) {
                float4 pp = sp[s + 32 * u];
                float4 gg = sg[s + 32 * u];
                float dx = q.x - pp.x, dy = q.y - pp.y;
                float d  = fast_sqrtf(fmaf(dx, dx, dy * dy));
                p0 += fast_exp2f(fmaf(-cL2, d, cB));
                dx = q.x - pp.z; dy = q.y - pp.w;
                d  = fast_sqrtf(fmaf(dx, dx, dy * dy));
                p1 += fast_exp2f(fmaf(-cL2, d, cB));
                dx = q.x - gg.x; dy = q.y - gg.y;
                d  = fast_sqrtf(fmaf(dx, dx, dy * dy));
                n0 += fast_exp2f(fmaf(-cL2, d, cB));
                dx = q.x - gg.z; dy = q.y - gg.w;
                d  = fast_sqrtf(fmaf(dx, dx, dy * dy));
                n1 += fast_exp2f(fmaf(-cL2, d, cB));
            }
        }
    }

    float sump = p0 + p1;
    float sumn = n0 + n1;
    #pragma unroll
    for (int m = 1; m < 32; m <<= 1) {
        sump += __shfl_xor(sump, m, 32);
        sumn += __shfl_xor(sumn, m, 32);
    }

    if (s == 0) {
        out[i] = Tl2 * (fast_log2f(sumn) - fast_log2f(sump));
    }
}

// ---------------------------------------------------------------------------
extern "C" void kernel_launch(void* const* d_in, const int* in_sizes, int n_in,
                              void* d_out, int out_size, void* d_ws, size_t ws_size,
                              hipStream_t stream) {
    const float* pos = (const float*)d_in[0];
    const float* z   = (const float*)d_in[1];
    const float* W1  = (const float*)d_in[2];
    const float* b1  = (const float*)d_in[3];
    const float* W2  = (const float*)d_in[4];
    const float* b2  = (const float*)d_in[5];
    const float* W3  = (const float*)d_in[6];
    const float* b3  = (const float*)d_in[7];
    const float* W4  = (const float*)d_in[8];
    const float* b4  = (const float*)d_in[9];
    const float* W5  = (const float*)d_in[10];
    const float* b5  = (const float*)d_in[11];

    char* ws = (char*)d_ws;
    float*          gen     = (float*)(ws);                    // 131072 B
    unsigned short* pk      = (unsigned short*)(ws + 131072);  // 819200 B
    float2*         posS    = (float2*)(ws + 950272);          // 131072 B
    float2*         genS    = (float2*)(ws + 1081344);         // 131072 B
    int*            genOrig = (int*)   (ws + 1212416);         // 65536 B
    float4*         posB    = (float4*)(ws + 1277952);         // 4096 B
    float4*         genB    = (float4*)(ws + 1282048);         // 4096 B
    int*            cnt     = (int*)   (ws + 1286144);         // 8192 B
    int*            cursor  = (int*)   (ws + 1294336);         // 8192 B
    float* outp = (float*)d_out;

    const size_t WS_MFMA   = 950272;
    const size_t WS_BINNED = 1302528;

    // MLP
    if (ws_size >= WS_MFMA) {
        pack_kernel<<<100, 256, 0, stream>>>(W1, W2, W3, W4, pk);
        mlp_mfma_kernel<<<N_PTS / 32, 512, 0, stream>>>(z, pk, b1, b2, b3, b4,
                                                        W5, b5, gen);
    } else {
        mlp_kernel<<<N_PTS / 64, 1024, 0, stream>>>(z, W1, b1, W2, b2, W3, b3,
                                                    W4, b4, W5, b5, gen);
    }

    // Energy
    if (ws_size >= WS_BINNED) {
        zero_kernel<<<4, 512, 0, stream>>>(cnt);
        hist_kernel<<<64, 512, 0, stream>>>(pos, gen, cnt);
        scan_kernel<<<2, 1024, 0, stream>>>(cnt, cursor);
        scatter_kernel<<<64, 512, 0, stream>>>(pos, gen, cursor,
                                               posS, genS, genOrig);
        bbox_kernel<<<2, 256, 0, stream>>>(posS, genS, posB, genB);
        energy_binned<<<N_PTS / 16, 512, 0, stream>>>(posS, genS, genOrig,
                                                      posB, genB, outp);
    } else {
        energy_kernel<<<N_PTS / 16, 512, 0, stream>>>(gen, pos, outp);
    }
}

// Round 9
// 300.802 us; speedup vs baseline: 1.6950x; 1.6950x over previous
//
#include <hip/hip_runtime.h>
#include <hip/hip_bf16.h>

#define N_PTS 16384
#define TEMP_F 0.05f
#define RCUT 0.8f

typedef __attribute__((ext_vector_type(8))) short bf16x8;
typedef __attribute__((ext_vector_type(4))) float f32x4;

__device__ __forceinline__ float selu_f(float x) {
    const float scale = 1.0507009873554805f;
    const float alpha = 1.6732632423543772f;
    return x > 0.f ? scale * x : scale * alpha * (__expf(x) - 1.f);
}

__device__ __forceinline__ float fast_sqrtf(float x) {
#if __has_builtin(__builtin_amdgcn_sqrtf)
    return __builtin_amdgcn_sqrtf(x);
#else
    return sqrtf(x);
#endif
}

__device__ __forceinline__ float fast_exp2f(float x) {
#if __has_builtin(__builtin_amdgcn_exp2f)
    return __builtin_amdgcn_exp2f(x);
#else
    return exp2f(x);
#endif
}

__device__ __forceinline__ float fast_log2f(float x) {
#if __has_builtin(__builtin_amdgcn_logf)
    return __builtin_amdgcn_logf(x);
#else
    return log2f(x);
#endif
}

__device__ __forceinline__ f32x4 mfma_bf16(bf16x8 a, bf16x8 b, f32x4 c) {
    return __builtin_amdgcn_mfma_f32_16x16x32_bf16(a, b, c, 0, 0, 0);
}

__device__ __forceinline__ void split_bf16(float v, unsigned short& hi, unsigned short& lo) {
    unsigned u = __float_as_uint(v);
    hi = (unsigned short)(u >> 16);
    float ah = __uint_as_float(u & 0xFFFF0000u);
    lo = (unsigned short)(__float_as_uint(v - ah) >> 16);
}

// Morton cell: 32x32 grid over [-6.4, 6.4], h=0.4, Z-order so 64-point
// subtiles of the sorted array are ~2x2 cell blocks (compact bboxes).
// Clamping affects only locality, never correctness (bboxes use true coords).
__device__ __forceinline__ unsigned spread5(unsigned x) {
    x &= 31u;
    x = (x | (x << 8)) & 0x00FF00FFu;
    x = (x | (x << 4)) & 0x0F0F0F0Fu;
    x = (x | (x << 2)) & 0x33333333u;
    x = (x | (x << 1)) & 0x55555555u;
    return x;
}
__device__ __forceinline__ int mortonCell(float x, float y) {
    int cx = (int)floorf((x + 6.4f) * 2.5f);
    int cy = (int)floorf((y + 6.4f) * 2.5f);
    cx = min(31, max(0, cx));
    cy = min(31, max(0, cy));
    return (int)(spread5((unsigned)cx) | (spread5((unsigned)cy) << 1));
}

// ---------------------------------------------------------------------------
// pack_kernel (unchanged)
// ---------------------------------------------------------------------------
__global__ __launch_bounds__(256) void pack_kernel(
    const float* __restrict__ W1, const float* __restrict__ W2,
    const float* __restrict__ W3, const float* __restrict__ W4,
    unsigned short* __restrict__ pk)
{
    int idx = blockIdx.x * 256 + threadIdx.x;   // 0..25599
    if (idx >= 25600) return;
    const float* src;
    unsigned short *dh, *dl;
    int nt, kc, l, KC;
    if (idx < 1024) {
        src = W1; dh = pk; dl = pk + 8192; KC = 1;
        nt = idx >> 6; kc = 0; l = idx & 63;
    } else {
        int t2 = idx - 1024;
        int ly = t2 >> 13;
        int r2 = t2 & 8191;
        src = (ly == 0) ? W2 : (ly == 1) ? W3 : W4;
        dh = pk + 16384 + ly * 131072;
        dl = dh + 65536;
        KC = 8;
        nt = r2 >> 9; kc = (r2 >> 6) & 7; l = r2 & 63;
    }
    int lr = l & 15, lq = l >> 4;
    int n = nt * 16 + lr;
    bf16x8 hv, lv;
    #pragma unroll
    for (int e = 0; e < 8; e++) {
        int k = kc * 32 + lq * 8 + e;
        float v = src[k * 256 + n];
        unsigned short hb, lb;
        split_bf16(v, hb, lb);
        hv[e] = (short)hb; lv[e] = (short)lb;
    }
    int base = ((nt * KC + kc) * 64 + l) * 8;
    *(bf16x8*)(dh + base) = hv;
    *(bf16x8*)(dl + base) = lv;
}

// ---------------------------------------------------------------------------
// mlp_mfma_kernel v5 (unchanged from R7)
// ---------------------------------------------------------------------------
__global__ __launch_bounds__(512) void mlp_mfma_kernel(
    const float* __restrict__ z,
    const unsigned short* __restrict__ pk,
    const float* __restrict__ b1, const float* __restrict__ b2,
    const float* __restrict__ b3, const float* __restrict__ b4,
    const float* __restrict__ W5, const float* __restrict__ b5,
    float* __restrict__ gen)
{
    __shared__ __align__(16) unsigned short Hh[32 * 256];
    __shared__ __align__(16) unsigned short Hl[32 * 256];

    const int t  = threadIdx.x;
    const int l  = t & 63;
    const int wv = t >> 6;
    const int lr = l & 15;
    const int lq = l >> 4;
    const int row0 = blockIdx.x * 32;
    const int bro  = blockIdx.x & 7;
    const int wp   = (wv + (blockIdx.x >> 3)) & 7;

    f32x4 acc[2][2];

    {
        bf16x8 ah[2], al[2];
        #pragma unroll
        for (int m = 0; m < 2; m++) {
            const float* zp = z + (row0 + m * 16 + lr) * 32 + lq * 8;
            f32x4 z0 = *(const f32x4*)(zp);
            f32x4 z1 = *(const f32x4*)(zp + 4);
            #pragma unroll
            for (int e = 0; e < 8; e++) {
                float v = (e < 4) ? z0[e] : z1[e - 4];
                unsigned short hb, lb;
                split_bf16(v, hb, lb);
                ah[m][e] = (short)hb; al[m][e] = (short)lb;
            }
        }
        #pragma unroll
        for (int n2 = 0; n2 < 2; n2++) {
            float bv = b1[wp * 32 + n2 * 16 + lr];
            #pragma unroll
            for (int m = 0; m < 2; m++) acc[m][n2] = (f32x4){bv, bv, bv, bv};
        }
        const bf16x8* B1h = (const bf16x8*)(pk);
        const bf16x8* B1l = (const bf16x8*)(pk + 8192);
        #pragma unroll
        for (int n2 = 0; n2 < 2; n2++) {
            int nt = wp * 2 + n2;
            bf16x8 bh = B1h[nt * 64 + l];
            bf16x8 bl = B1l[nt * 64 + l];
            #pragma unroll
            for (int m = 0; m < 2; m++) {
                acc[m][n2] = mfma_bf16(ah[m], bh, acc[m][n2]);
                acc[m][n2] = mfma_bf16(ah[m], bl, acc[m][n2]);
                acc[m][n2] = mfma_bf16(al[m], bh, acc[m][n2]);
            }
        }
        #pragma unroll
        for (int m = 0; m < 2; m++) {
            #pragma unroll
            for (int n2 = 0; n2 < 2; n2++) {
                #pragma unroll
                for (int r = 0; r < 4; r++) {
                    float v = selu_f(acc[m][n2][r]);
                    int rowo = m * 16 + lq * 4 + r;
                    int n = wp * 32 + n2 * 16 + lr;
                    int o = (2 * n) ^ ((rowo & 7) << 4);
                    unsigned short hb, lb;
                    split_bf16(v, hb, lb);
                    Hh[rowo * 256 + (o >> 1)] = hb;
                    Hl[rowo * 256 + (o >> 1)] = lb;
                }
            }
        }
    }
    __syncthreads();

    #pragma unroll 1
    for (int ly = 0; ly < 3; ly++) {
        const unsigned short* wbase = pk + 16384 + ly * 131072;
        const bf16x8* Bh = (const bf16x8*)(wbase);
        const bf16x8* Bl = (const bf16x8*)(wbase + 65536);
        const float* bb = (ly == 0) ? b2 : (ly == 1) ? b3 : b4;
        #pragma unroll
        for (int n2 = 0; n2 < 2; n2++) {
            float bv = bb[wp * 32 + n2 * 16 + lr];
            #pragma unroll
            for (int m = 0; m < 2; m++) acc[m][n2] = (f32x4){bv, bv, bv, bv};
        }
        #pragma unroll 4
        for (int kci = 0; kci < 8; kci++) {
            int kc = (kci + bro) & 7;
            bf16x8 ah[2], al[2];
            #pragma unroll
            for (int m = 0; m < 2; m++) {
                int arow = m * 16 + lr;
                int o = (kc * 64 + lq * 16) ^ ((arow & 7) << 4);
                ah[m] = *(const bf16x8*)(Hh + arow * 256 + (o >> 1));
                al[m] = *(const bf16x8*)(Hl + arow * 256 + (o >> 1));
            }
            #pragma unroll
            for (int n2 = 0; n2 < 2; n2++) {
                int nt = wp * 2 + n2;
                bf16x8 bh = Bh[(nt * 8 + kc) * 64 + l];
                bf16x8 bl = Bl[(nt * 8 + kc) * 64 + l];
                #pragma unroll
                for (int m = 0; m < 2; m++) {
                    acc[m][n2] = mfma_bf16(ah[m], bh, acc[m][n2]);
                    acc[m][n2] = mfma_bf16(ah[m], bl, acc[m][n2]);
                    acc[m][n2] = mfma_bf16(al[m], bh, acc[m][n2]);
                }
            }
        }
        __syncthreads();
        #pragma unroll
        for (int m = 0; m < 2; m++) {
            #pragma unroll
            for (int n2 = 0; n2 < 2; n2++) {
                #pragma unroll
                for (int r = 0; r < 4; r++) {
                    float v = selu_f(acc[m][n2][r]);
                    int rowo = m * 16 + lq * 4 + r;
                    int n = wp * 32 + n2 * 16 + lr;
                    int o = (2 * n) ^ ((rowo & 7) << 4);
                    unsigned short hb, lb;
                    split_bf16(v, hb, lb);
                    Hh[rowo * 256 + (o >> 1)] = hb;
                    Hl[rowo * 256 + (o >> 1)] = lb;
                }
            }
        }
        __syncthreads();
    }

    if (t < 64) {
        int row = t & 31;
        int d = t >> 5;
        float sum = b5[d];
        #pragma unroll 4
        for (int k = 0; k < 256; k += 8) {
            int o = (2 * k) ^ ((row & 7) << 4);
            bf16x8 hh = *(const bf16x8*)(Hh + row * 256 + (o >> 1));
            bf16x8 ll = *(const bf16x8*)(Hl + row * 256 + (o >> 1));
            #pragma unroll
            for (int e = 0; e < 8; e++) {
                float hv = __uint_as_float(((unsigned)(unsigned short)hh[e]) << 16)
                         + __uint_as_float(((unsigned)(unsigned short)ll[e]) << 16);
                sum = fmaf(hv, W5[(k + e) * 2 + d], sum);
            }
        }
        gen[(row0 + row) * 2 + d] = sum;
    }
}

// ---------------------------------------------------------------------------
// Fallback fp32 MLP
// ---------------------------------------------------------------------------
__global__ __launch_bounds__(1024) void mlp_kernel(
    const float* __restrict__ z,
    const float* __restrict__ W1, const float* __restrict__ b1,
    const float* __restrict__ W2, const float* __restrict__ b2,
    const float* __restrict__ W3, const float* __restrict__ b3,
    const float* __restrict__ W4, const float* __restrict__ b4,
    const float* __restrict__ W5, const float* __restrict__ b5,
    float* __restrict__ gen)
{
    __shared__ float h[256 * 64];

    const int t = threadIdx.x;
    const int r = t & 63;
    const int w = __builtin_amdgcn_readfirstlane(t >> 6);
    const int c0 = w * 16;
    const int row0 = blockIdx.x * 64;

    #pragma unroll
    for (int e = 0; e < 2; e++) {
        int f  = t + e * 1024;
        int rz = f >> 5;
        int kz = f & 31;
        h[kz * 64 + rz] = z[(row0 + rz) * 32 + kz];
    }
    __syncthreads();

    float acc[16];

    #pragma unroll
    for (int j = 0; j < 16; j++) acc[j] = b1[c0 + j];
    #pragma unroll 8
    for (int k = 0; k < 32; k++) {
        float hv = h[k * 64 + r];
        const float* Wr = W1 + k * 256 + c0;
        #pragma unroll
        for (int j = 0; j < 16; j++) acc[j] = fmaf(hv, Wr[j], acc[j]);
    }
    __syncthreads();
    #pragma unroll
    for (int j = 0; j < 16; j++) h[(c0 + j) * 64 + r] = selu_f(acc[j]);
    __syncthreads();

    for (int layer = 0; layer < 3; layer++) {
        const float* W = (layer == 0) ? W2 : (layer == 1) ? W3 : W4;
        const float* b = (layer == 0) ? b2 : (layer == 1) ? b3 : b4;
        #pragma unroll
        for (int j = 0; j < 16; j++) acc[j] = b[c0 + j];
        #pragma unroll 4
        for (int k = 0; k < 256; k++) {
            float hv = h[k * 64 + r];
            const float* Wr = W + k * 256 + c0;
            #pragma unroll
            for (int j = 0; j < 16; j++) acc[j] = fmaf(hv, Wr[j], acc[j]);
        }
        __syncthreads();
        #pragma unroll
        for (int j = 0; j < 16; j++) h[(c0 + j) * 64 + r] = selu_f(acc[j]);
        __syncthreads();
    }

    float p0 = 0.f, p1 = 0.f;
    #pragma unroll
    for (int kk = 0; kk < 16; kk++) {
        int k = c0 + kk;
        float hv = h[k * 64 + r];
        p0 = fmaf(hv, W5[k * 2 + 0], p0);
        p1 = fmaf(hv, W5[k * 2 + 1], p1);
    }
    __syncthreads();
    h[(0 * 16 + w) * 64 + r] = p0;
    h[(1 * 16 + w) * 64 + r] = p1;
    __syncthreads();
    if (t < 128) {
        int d  = t >> 6;
        int rr = t & 63;
        float sum = b5[d];
        #pragma unroll
        for (int ss = 0; ss < 16; ss++) sum += h[(d * 16 + ss) * 64 + rr];
        gen[(row0 + rr) * 2 + d] = sum;
    }
}

// ---------------------------------------------------------------------------
// sortbin_kernel: ONE dispatch, 2 blocks (block 0 = pos, block 1 = gen).
// Counting sort by Morton cell entirely with LDS atomics (R8's global-atomic
// hotspot: ~420 same-address L2 RMWs on the mode cell = the dark-matter
// suspect; LDS same-address RMW is ~100x cheaper). Points staged in regs.
// Then per-64-point-subtile bboxes (4 threads/subtile + shfl combine).
// ---------------------------------------------------------------------------
__global__ __launch_bounds__(1024) void sortbin_kernel(
    const float* __restrict__ pos, const float* __restrict__ gen,
    float2* __restrict__ posS, float2* __restrict__ genS,
    int* __restrict__ genOrig,
    float4* __restrict__ posB, float4* __restrict__ genB)
{
    __shared__ int hist[1024];
    __shared__ int cur[1024];

    const int t = threadIdx.x;
    const int side = blockIdx.x;                 // 0 pos, 1 gen
    const float* src = side ? gen : pos;
    float2* dst = side ? genS : posS;

    hist[t] = 0;
    __syncthreads();

    float px[16], py[16];
    int   pc[16];
    #pragma unroll
    for (int it = 0; it < 16; it++) {
        int i = it * 1024 + t;
        float x = src[2 * i], y = src[2 * i + 1];
        px[it] = x; py[it] = y;
        int c = mortonCell(x, y);
        pc[it] = c;
        atomicAdd(&hist[c], 1);
    }
    __syncthreads();

    // exclusive scan (Hillis-Steele, 1024)
    int own = hist[t];
    cur[t] = own;
    __syncthreads();
    for (int off = 1; off < 1024; off <<= 1) {
        int u = (t >= off) ? cur[t - off] : 0;
        __syncthreads();
        cur[t] += u;
        __syncthreads();
    }
    int excl = cur[t] - own;
    __syncthreads();
    cur[t] = excl;
    __syncthreads();

    // scatter
    #pragma unroll
    for (int it = 0; it < 16; it++) {
        int p = atomicAdd(&cur[pc[it]], 1);
        dst[p] = make_float2(px[it], py[it]);
        if (side) genOrig[p] = it * 1024 + t;
    }
    __threadfence();
    __syncthreads();

    // bboxes: 256 subtiles x 64 pts; 4 threads/subtile, 16 pts each
    {
        int st = t >> 2, qq = t & 3;
        float x0 = 1e30f, y0 = 1e30f, x1 = -1e30f, y1 = -1e30f;
        #pragma unroll 4
        for (int e = 0; e < 16; e++) {
            float2 p = dst[st * 64 + qq * 16 + e];
            x0 = fminf(x0, p.x); x1 = fmaxf(x1, p.x);
            y0 = fminf(y0, p.y); y1 = fmaxf(y1, p.y);
        }
        #pragma unroll
        for (int m = 1; m < 4; m <<= 1) {
            x0 = fminf(x0, __shfl_xor(x0, m));
            y0 = fminf(y0, __shfl_xor(y0, m));
            x1 = fmaxf(x1, __shfl_xor(x1, m));
            y1 = fmaxf(y1, __shfl_xor(y1, m));
        }
        if (qq == 0) (side ? genB : posB)[st] = make_float4(x0, y0, x1, y1);
    }
}

// ---------------------------------------------------------------------------
// energy_binned v2: culled softmin-distance energy on Morton-sorted data.
// dmin_ub per query = TRUE distance to nearest candidate in the query's
// own-rank subtile on each side (a real distance -> valid upper bound on
// dmin; loose only if gen/pos distributions diverge -> slower, never wrong).
// thr(side) = max over the block's 16 queries of dmin_ub + RCUT.
// Keep subtile iff mindist(qbbox, stbbox) <= thr. Coverage: any point with
// d <= dmin+RCUT has mindist <= d <= thr -> kept. Own subtile mindist=0 ->
// sums never empty. Dropped-term bound: N*2^(-28.85*RCUT) -> <=9.5e-5 energy
// error. Per-pair math identical to the exact kernel.
// ---------------------------------------------------------------------------
__global__ __launch_bounds__(512) void energy_binned(
    const float2* __restrict__ posS, const float2* __restrict__ genS,
    const int* __restrict__ genOrig,
    const float4* __restrict__ posB, const float4* __restrict__ genB,
    float* __restrict__ out)
{
    __shared__ float qb[4];
    __shared__ float qxA[16], qyA[16];
    __shared__ float dminA[32];          // [0..15]=pos, [16..31]=gen
    __shared__ float thrS[2];
    __shared__ int   wcnt[8], wbase[8], nPG[2];
    __shared__ unsigned short listP[256], listG[256];

    const int t  = threadIdx.x;
    const int b  = blockIdx.x;
    const int s  = t & 31;
    const int rl = t >> 5;
    const int i_s = b * 16 + rl;         // sorted query index
    const int st0 = b >> 2;              // own-rank subtile (uniform in block)

    const float2 q = genS[i_s];
    const float4* posS4 = (const float4*)posS;
    const float4* genS4 = (const float4*)genS;

    // --- A0: per-query dmin upper bounds from own-rank subtiles -----------
    {
        float4 gg = genS4[st0 * 32 + s];
        int j0 = st0 * 64 + 2 * s;
        float dx = q.x - gg.x, dy = q.y - gg.y;
        float d0 = fast_sqrtf(fmaf(dx, dx, dy * dy));
        if (j0 == i_s) d0 = 1e30f;
        dx = q.x - gg.z; dy = q.y - gg.w;
        float d1 = fast_sqrtf(fmaf(dx, dx, dy * dy));
        if (j0 + 1 == i_s) d1 = 1e30f;
        float dmg = fminf(d0, d1);

        float4 pp = posS4[st0 * 32 + s];
        dx = q.x - pp.x; dy = q.y - pp.y;
        float e0 = fast_sqrtf(fmaf(dx, dx, dy * dy));
        dx = q.x - pp.z; dy = q.y - pp.w;
        float e1 = fast_sqrtf(fmaf(dx, dx, dy * dy));
        float dmp = fminf(e0, e1);

        #pragma unroll
        for (int m = 1; m < 32; m <<= 1) {
            dmg = fminf(dmg, __shfl_xor(dmg, m, 32));
            dmp = fminf(dmp, __shfl_xor(dmp, m, 32));
        }
        if (s == 0) {
            dminA[rl] = dmp; dminA[16 + rl] = dmg;
            qxA[rl] = q.x;   qyA[rl] = q.y;
        }
    }
    __syncthreads();
    if (t == 0) {
        float tp = 0.f, tg = 0.f;
        float x0 = 1e30f, y0 = 1e30f, x1 = -1e30f, y1 = -1e30f;
        for (int r = 0; r < 16; r++) {
            tp = fmaxf(tp, dminA[r]);
            tg = fmaxf(tg, dminA[16 + r]);
            x0 = fminf(x0, qxA[r]); x1 = fmaxf(x1, qxA[r]);
            y0 = fminf(y0, qyA[r]); y1 = fmaxf(y1, qyA[r]);
        }
        thrS[0] = tp + RCUT; thrS[1] = tg + RCUT;
        qb[0] = x0; qb[1] = y0; qb[2] = x1; qb[3] = y1;
    }
    __syncthreads();
    const float qx0 = qb[0], qy0 = qb[1], qx1 = qb[2], qy1 = qb[3];

    // --- A: bbox filter, ballot compaction --------------------------------
    const int stl  = t & 255;
    const int side = t >> 8;
    float4 bb = side ? genB[stl] : posB[stl];
    float dxo = fmaxf(fmaxf(bb.x - qx1, qx0 - bb.z), 0.f);
    float dyo = fmaxf(fmaxf(bb.y - qy1, qy0 - bb.w), 0.f);
    float md2 = dxo * dxo + dyo * dyo;
    float thr = thrS[side];
    bool keep = md2 <= thr * thr;
    unsigned long long mk = __ballot(keep);
    int wv = t >> 6;
    if ((t & 63) == 0) wcnt[wv] = __popcll(mk);
    __syncthreads();
    if (t == 0) {
        int a = 0;
        for (int w = 0; w < 4; w++) { wbase[w] = a; a += wcnt[w]; }
        nPG[0] = a; a = 0;
        for (int w = 4; w < 8; w++) { wbase[w] = a; a += wcnt[w]; }
        nPG[1] = a;
    }
    __syncthreads();
    if (keep) {
        int p = wbase[wv] + __popcll(mk & ((1ull << (t & 63)) - 1ull));
        if (side == 0) listP[p] = (unsigned short)stl;
        else           listG[p] = (unsigned short)stl;
    }
    __syncthreads();
    const int nP = nPG[0], nG = nPG[1];

    const float cL2 = 28.853900817779268f;   // 1/(T*ln2)
    const float Tl2 = 0.034657359027997264f; // T*ln2
    const float cB  = 57.707801635558536f;   // cL2 * 2.0

    float sump = 0.f, sumn = 0.f;

    #pragma unroll 2
    for (int idx = 0; idx < nP; idx++) {
        int st = listP[idx];
        float4 pp = posS4[st * 32 + s];
        float dx = q.x - pp.x, dy = q.y - pp.y;
        float d  = fast_sqrtf(fmaf(dx, dx, dy * dy));
        sump += fast_exp2f(fmaf(-cL2, d, cB));
        dx = q.x - pp.z; dy = q.y - pp.w;
        d  = fast_sqrtf(fmaf(dx, dx, dy * dy));
        sump += fast_exp2f(fmaf(-cL2, d, cB));
    }
    #pragma unroll 2
    for (int idx = 0; idx < nG; idx++) {
        int st = listG[idx];
        float4 gg = genS4[st * 32 + s];
        int j0 = st * 64 + 2 * s;
        float dx = q.x - gg.x, dy = q.y - gg.y;
        float d  = fast_sqrtf(fmaf(dx, dx, dy * dy));
        float e0 = fast_exp2f(fmaf(-cL2, d, cB));
        sumn += (j0 == i_s) ? 0.f : e0;
        dx = q.x - gg.z; dy = q.y - gg.w;
        d  = fast_sqrtf(fmaf(dx, dx, dy * dy));
        float e1 = fast_exp2f(fmaf(-cL2, d, cB));
        sumn += (j0 + 1 == i_s) ? 0.f : e1;
    }

    #pragma unroll
    for (int m = 1; m < 32; m <<= 1) {
        sump += __shfl_xor(sump, m, 32);
        sumn += __shfl_xor(sumn, m, 32);
    }
    if (s == 0) {
        out[genOrig[i_s]] = Tl2 * (fast_log2f(sumn) - fast_log2f(sump));
    }
}

// ---------------------------------------------------------------------------
// Exact energy kernel (fallback)
// ---------------------------------------------------------------------------
__global__ __launch_bounds__(512) void energy_kernel(
    const float* __restrict__ gen,
    const float* __restrict__ pos,
    float* __restrict__ out)
{
    __shared__ float4 sp[512];
    __shared__ float4 sg[512];

    const int t  = threadIdx.x;
    const int s  = t & 31;
    const int rl = t >> 5;
    const int i  = blockIdx.x * 16 + rl;
    const int diagBase = ((blockIdx.x * 16) >> 10) << 10;

    const float2 q = ((const float2*)gen)[i];

    const float cL2 = 28.853900817779268f;
    const float Tl2 = 0.034657359027997264f;
    const float cB  = 57.707801635558536f;

    float p0 = 0.f, p1 = 0.f, n0 = 0.f, n1 = 0.f;

    for (int base = 0; base < N_PTS; base += 1024) {
        __syncthreads();
        sp[t] = ((const float4*)pos)[base / 2 + t];
        sg[t] = ((const float4*)gen)[base / 2 + t];
        __syncthreads();
        if (base == diagBase) {
            #pragma unroll 4
            for (int u = 0; u < 16; u++) {
                int j = base + 2 * (s + 32 * u);
                float4 pp = sp[s + 32 * u];
                float4 gg = sg[s + 32 * u];
                float dx = q.x - pp.x, dy = q.y - pp.y;
                float d  = fast_sqrtf(fmaf(dx, dx, dy * dy));
                p0 += fast_exp2f(fmaf(-cL2, d, cB));
                dx = q.x - pp.z; dy = q.y - pp.w;
                d  = fast_sqrtf(fmaf(dx, dx, dy * dy));
                p1 += fast_exp2f(fmaf(-cL2, d, cB));
                dx = q.x - gg.x; dy = q.y - gg.y;
                d  = fast_sqrtf(fmaf(dx, dx, dy * dy));
                float e0 = fast_exp2f(fmaf(-cL2, d, cB));
                n0 += (j == i) ? 0.f : e0;
                dx = q.x - gg.z; dy = q.y - gg.w;
                d  = fast_sqrtf(fmaf(dx, dx, dy * dy));
                float e1 = fast_exp2f(fmaf(-cL2, d, cB));
                n1 += (j + 1 == i) ? 0.f : e1;
            }
        } else {
            #pragma unroll 4
            for (int u = 0; u < 16; u++) {
                float4 pp = sp[s + 32 * u];
                float4 gg = sg[s + 32 * u];
                float dx = q.x - pp.x, dy = q.y - pp.y;
                float d  = fast_sqrtf(fmaf(dx, dx, dy * dy));
                p0 += fast_exp2f(fmaf(-cL2, d, cB));
                dx = q.x - pp.z; dy = q.y - pp.w;
                d  = fast_sqrtf(fmaf(dx, dx, dy * dy));
                p1 += fast_exp2f(fmaf(-cL2, d, cB));
                dx = q.x - gg.x; dy = q.y - gg.y;
                d  = fast_sqrtf(fmaf(dx, dx, dy * dy));
                n0 += fast_exp2f(fmaf(-cL2, d, cB));
                dx = q.x - gg.z; dy = q.y - gg.w;
                d  = fast_sqrtf(fmaf(dx, dx, dy * dy));
                n1 += fast_exp2f(fmaf(-cL2, d, cB));
            }
        }
    }

    float sump = p0 + p1;
    float sumn = n0 + n1;
    #pragma unroll
    for (int m = 1; m < 32; m <<= 1) {
        sump += __shfl_xor(sump, m, 32);
        sumn += __shfl_xor(sumn, m, 32);
    }

    if (s == 0) {
        out[i] = Tl2 * (fast_log2f(sumn) - fast_log2f(sump));
    }
}

// ---------------------------------------------------------------------------
extern "C" void kernel_launch(void* const* d_in, const int* in_sizes, int n_in,
                              void* d_out, int out_size, void* d_ws, size_t ws_size,
                              hipStream_t stream) {
    const float* pos = (const float*)d_in[0];
    const float* z   = (const float*)d_in[1];
    const float* W1  = (const float*)d_in[2];
    const float* b1  = (const float*)d_in[3];
    const float* W2  = (const float*)d_in[4];
    const float* b2  = (const float*)d_in[5];
    const float* W3  = (const float*)d_in[6];
    const float* b3  = (const float*)d_in[7];
    const float* W4  = (const float*)d_in[8];
    const float* b4  = (const float*)d_in[9];
    const float* W5  = (const float*)d_in[10];
    const float* b5  = (const float*)d_in[11];

    char* ws = (char*)d_ws;
    float*          gen     = (float*)(ws);                    // 131072 B
    unsigned short* pk      = (unsigned short*)(ws + 131072);  // 819200 B
    float2*         posS    = (float2*)(ws + 950272);          // 131072 B
    float2*         genS    = (float2*)(ws + 1081344);         // 131072 B
    int*            genOrig = (int*)   (ws + 1212416);         // 65536 B
    float4*         posB    = (float4*)(ws + 1277952);         // 4096 B
    float4*         genB    = (float4*)(ws + 1282048);         // 4096 B
    float* outp = (float*)d_out;

    const size_t WS_MFMA   = 950272;
    const size_t WS_BINNED = 1286144;

    if (ws_size >= WS_MFMA) {
        pack_kernel<<<100, 256, 0, stream>>>(W1, W2, W3, W4, pk);
        mlp_mfma_kernel<<<N_PTS / 32, 512, 0, stream>>>(z, pk, b1, b2, b3, b4,
                                                        W5, b5, gen);
    } else {
        mlp_kernel<<<N_PTS / 64, 1024, 0, stream>>>(z, W1, b1, W2, b2, W3, b3,
                                                    W4, b4, W5, b5, gen);
    }

    if (ws_size >= WS_BINNED) {
        sortbin_kernel<<<2, 1024, 0, stream>>>(pos, gen, posS, genS,
                                               genOrig, posB, genB);
        energy_binned<<<N_PTS / 16, 512, 0, stream>>>(posS, genS, genOrig,
                                                      posB, genB, outp);
    } else {
        energy_kernel<<<N_PTS / 16, 512, 0, stream>>>(gen, pos, outp);
    }
}

// Round 11
// 239.053 us; speedup vs baseline: 2.1328x; 1.2583x over previous
//
#include <hip/hip_runtime.h>
#include <hip/hip_bf16.h>

#define N_PTS 16384
#define TEMP_F 0.05f

typedef __attribute__((ext_vector_type(8))) short bf16x8;
typedef __attribute__((ext_vector_type(4))) float f32x4;

__device__ __forceinline__ float selu_f(float x) {
    const float scale = 1.0507009873554805f;
    const float alpha = 1.6732632423543772f;
    return x > 0.f ? scale * x : scale * alpha * (__expf(x) - 1.f);
}

__device__ __forceinline__ float fast_sqrtf(float x) {
#if __has_builtin(__builtin_amdgcn_sqrtf)
    return __builtin_amdgcn_sqrtf(x);   // v_sqrt_f32
#else
    return sqrtf(x);
#endif
}

__device__ __forceinline__ float fast_exp2f(float x) {
#if __has_builtin(__builtin_amdgcn_exp2f)
    return __builtin_amdgcn_exp2f(x);   // v_exp_f32
#else
    return exp2f(x);
#endif
}

__device__ __forceinline__ float fast_log2f(float x) {
#if __has_builtin(__builtin_amdgcn_logf)
    return __builtin_amdgcn_logf(x);    // v_log_f32
#else
    return log2f(x);
#endif
}

__device__ __forceinline__ f32x4 mfma_bf16(bf16x8 a, bf16x8 b, f32x4 c) {
    return __builtin_amdgcn_mfma_f32_16x16x32_bf16(a, b, c, 0, 0, 0);
}

// split fp32 v into truncated-bf16 hi + bf16(residual) lo; hi+lo ~ 16-bit mantissa
__device__ __forceinline__ void split_bf16(float v, unsigned short& hi, unsigned short& lo) {
    unsigned u = __float_as_uint(v);
    hi = (unsigned short)(u >> 16);
    float ah = __uint_as_float(u & 0xFFFF0000u);
    lo = (unsigned short)(__float_as_uint(v - ah) >> 16);
}

// ---------------------------------------------------------------------------
// pack_kernel: COALESCED reads (thread per (k,n), consecutive lanes ->
// consecutive n), scattered 2B stores (fire-and-forget, no stall).
// Packed per-lane MFMA B-fragment order:
//   ushort index rem = ((nt*KC + kc)*64 + lq*16 + lr)*8 + e
//   with n = nt*16 + lr, k = kc*32 + lq*8 + e
// Region layout (ushort offsets): W1h:0 W1l:8192; layer ly in {0,1,2}:
//   h at 16384 + ly*131072, l = h + 65536
// ---------------------------------------------------------------------------
__global__ __launch_bounds__(256) void pack_kernel(
    const float* __restrict__ W1, const float* __restrict__ W2,
    const float* __restrict__ W3, const float* __restrict__ W4,
    unsigned short* __restrict__ pk)
{
    int idx = blockIdx.x * 256 + threadIdx.x;
    if (idx >= 204800) return;
    const float* src;
    unsigned short *dh, *dl;
    int k, n, KC;
    if (idx < 8192) {                       // W1: K=32
        src = W1; dh = pk; dl = pk + 8192; KC = 1;
        k = idx >> 8; n = idx & 255;
    } else {                                // W2..W4: K=256
        int t2 = idx - 8192;
        int ly = t2 >> 16;
        int r2 = t2 & 65535;
        src = (ly == 0) ? W2 : (ly == 1) ? W3 : W4;
        dh = pk + 16384 + ly * 131072;
        dl = dh + 65536;
        KC = 8;
        k = r2 >> 8; n = r2 & 255;
    }
    int nt = n >> 4, lr = n & 15;
    int kc = k >> 5, lq = (k >> 3) & 3, e = k & 7;
    int rem = ((nt * KC + kc) * 64 + lq * 16 + lr) * 8 + e;
    float v = src[k * 256 + n];
    unsigned short hb, lb;
    split_bf16(v, hb, lb);
    dh[rem] = hb;
    dl[rem] = lb;
}

// ---------------------------------------------------------------------------
// mlp_mfma_kernel v3 (best-measured config, 235.2us total): fused 5-layer MLP
// via split-bf16 MFMA (Ah*Bh + Ah*Bl + Al*Bh, fp32 accumulate).
// 32 rows/block -> grid 512; LDS 32KB; VGPR ~90 -> 2 blocks/CU; kc unroll 4.
// 8 waves; wave wv owns n-tiles {2wv,2wv+1} x 2 m-tiles; 12 MFMA/kc.
// LDS XOR swizzle byte^=((row&7)<<4) keeps b128 A-reads conflict-free.
// ---------------------------------------------------------------------------
__global__ __launch_bounds__(512) void mlp_mfma_kernel(
    const float* __restrict__ z,
    const unsigned short* __restrict__ pk,
    const float* __restrict__ b1, const float* __restrict__ b2,
    const float* __restrict__ b3, const float* __restrict__ b4,
    const float* __restrict__ W5, const float* __restrict__ b5,
    float* __restrict__ gen)
{
    __shared__ __align__(16) unsigned short Hh[32 * 256];   // 16 KB
    __shared__ __align__(16) unsigned short Hl[32 * 256];   // 16 KB

    const int t  = threadIdx.x;
    const int l  = t & 63;
    const int wv = t >> 6;          // 0..7: owns n-tiles {2wv, 2wv+1}
    const int lr = l & 15;          // fragment m (A) / n (B,D) index
    const int lq = l >> 4;          // 0..3: k-subblock / D row group
    const int row0 = blockIdx.x * 32;

    f32x4 acc[2][2];

    // ---------------- layer 1 (32 -> 256), K fits one MFMA ----------------
    {
        bf16x8 ah[2], al[2];
        #pragma unroll
        for (int m = 0; m < 2; m++) {
            const float* zp = z + (row0 + m * 16 + lr) * 32 + lq * 8;
            f32x4 z0 = *(const f32x4*)(zp);
            f32x4 z1 = *(const f32x4*)(zp + 4);
            #pragma unroll
            for (int e = 0; e < 8; e++) {
                float v = (e < 4) ? z0[e] : z1[e - 4];
                unsigned short hb, lb;
                split_bf16(v, hb, lb);
                ah[m][e] = (short)hb; al[m][e] = (short)lb;
            }
        }
        #pragma unroll
        for (int n2 = 0; n2 < 2; n2++) {
            float bv = b1[wv * 32 + n2 * 16 + lr];
            #pragma unroll
            for (int m = 0; m < 2; m++) acc[m][n2] = (f32x4){bv, bv, bv, bv};
        }
        const bf16x8* B1h = (const bf16x8*)(pk);
        const bf16x8* B1l = (const bf16x8*)(pk + 8192);
        #pragma unroll
        for (int n2 = 0; n2 < 2; n2++) {
            int nt = wv * 2 + n2;
            bf16x8 bh = B1h[nt * 64 + l];
            bf16x8 bl = B1l[nt * 64 + l];
            #pragma unroll
            for (int m = 0; m < 2; m++) {
                acc[m][n2] = mfma_bf16(ah[m], bh, acc[m][n2]);
                acc[m][n2] = mfma_bf16(ah[m], bl, acc[m][n2]);
                acc[m][n2] = mfma_bf16(al[m], bh, acc[m][n2]);
            }
        }
        // D layout (verified m89): col = lane&15, row = (lane>>4)*4 + r
        #pragma unroll
        for (int m = 0; m < 2; m++) {
            #pragma unroll
            for (int n2 = 0; n2 < 2; n2++) {
                #pragma unroll
                for (int r = 0; r < 4; r++) {
                    float v = selu_f(acc[m][n2][r]);
                    int rowo = m * 16 + lq * 4 + r;
                    int n = wv * 32 + n2 * 16 + lr;
                    int o = (2 * n) ^ ((rowo & 7) << 4);
                    unsigned short hb, lb;
                    split_bf16(v, hb, lb);
                    Hh[rowo * 256 + (o >> 1)] = hb;
                    Hl[rowo * 256 + (o >> 1)] = lb;
                }
            }
        }
    }
    __syncthreads();

    // ---------------- layers 2..4 (256 -> 256) ----------------
    #pragma unroll 1
    for (int ly = 0; ly < 3; ly++) {
        const unsigned short* wbase = pk + 16384 + ly * 131072;
        const bf16x8* Bh = (const bf16x8*)(wbase);
        const bf16x8* Bl = (const bf16x8*)(wbase + 65536);
        const float* bb = (ly == 0) ? b2 : (ly == 1) ? b3 : b4;
        #pragma unroll
        for (int n2 = 0; n2 < 2; n2++) {
            float bv = bb[wv * 32 + n2 * 16 + lr];
            #pragma unroll
            for (int m = 0; m < 2; m++) acc[m][n2] = (f32x4){bv, bv, bv, bv};
        }
        #pragma unroll 4
        for (int kc = 0; kc < 8; kc++) {
            bf16x8 ah[2], al[2];
            #pragma unroll
            for (int m = 0; m < 2; m++) {
                int arow = m * 16 + lr;
                int o = (kc * 64 + lq * 16) ^ ((arow & 7) << 4);
                ah[m] = *(const bf16x8*)(Hh + arow * 256 + (o >> 1));
                al[m] = *(const bf16x8*)(Hl + arow * 256 + (o >> 1));
            }
            #pragma unroll
            for (int n2 = 0; n2 < 2; n2++) {
                bf16x8 bh = Bh[((wv * 2 + n2) * 8 + kc) * 64 + l];
                bf16x8 bl = Bl[((wv * 2 + n2) * 8 + kc) * 64 + l];
                #pragma unroll
                for (int m = 0; m < 2; m++) {
                    acc[m][n2] = mfma_bf16(ah[m], bh, acc[m][n2]);
                    acc[m][n2] = mfma_bf16(ah[m], bl, acc[m][n2]);
                    acc[m][n2] = mfma_bf16(al[m], bh, acc[m][n2]);
                }
            }
        }
        __syncthreads();   // all waves done READING H before anyone overwrites
        #pragma unroll
        for (int m = 0; m < 2; m++) {
            #pragma unroll
            for (int n2 = 0; n2 < 2; n2++) {
                #pragma unroll
                for (int r = 0; r < 4; r++) {
                    float v = selu_f(acc[m][n2][r]);
                    int rowo = m * 16 + lq * 4 + r;
                    int n = wv * 32 + n2 * 16 + lr;
                    int o = (2 * n) ^ ((rowo & 7) << 4);
                    unsigned short hb, lb;
                    split_bf16(v, hb, lb);
                    Hh[rowo * 256 + (o >> 1)] = hb;
                    Hl[rowo * 256 + (o >> 1)] = lb;
                }
            }
        }
        __syncthreads();   // writes visible before next layer's reads
    }

    // ---------------- layer 5 (256 -> 2), VALU, 64 threads ----------------
    if (t < 64) {
        int row = t & 31;
        int d = t >> 5;
        float sum = b5[d];
        #pragma unroll 4
        for (int k = 0; k < 256; k += 8) {
            int o = (2 * k) ^ ((row & 7) << 4);
            bf16x8 hh = *(const bf16x8*)(Hh + row * 256 + (o >> 1));
            bf16x8 ll = *(const bf16x8*)(Hl + row * 256 + (o >> 1));
            #pragma unroll
            for (int e = 0; e < 8; e++) {
                float hv = __uint_as_float(((unsigned)(unsigned short)hh[e]) << 16)
                         + __uint_as_float(((unsigned)(unsigned short)ll[e]) << 16);
                sum = fmaf(hv, W5[(k + e) * 2 + d], sum);
            }
        }
        gen[(row0 + row) * 2 + d] = sum;
    }
}

// ---------------------------------------------------------------------------
// Fallback fp32 MLP — used only if workspace too small for packed weights.
// ---------------------------------------------------------------------------
__global__ __launch_bounds__(1024) void mlp_kernel(
    const float* __restrict__ z,
    const float* __restrict__ W1, const float* __restrict__ b1,
    const float* __restrict__ W2, const float* __restrict__ b2,
    const float* __restrict__ W3, const float* __restrict__ b3,
    const float* __restrict__ W4, const float* __restrict__ b4,
    const float* __restrict__ W5, const float* __restrict__ b5,
    float* __restrict__ gen)
{
    __shared__ float h[256 * 64];   // h[k*64 + r]

    const int t = threadIdx.x;
    const int r = t & 63;
    const int w = __builtin_amdgcn_readfirstlane(t >> 6);   // 0..15, uniform
    const int c0 = w * 16;
    const int row0 = blockIdx.x * 64;

    #pragma unroll
    for (int e = 0; e < 2; e++) {
        int f  = t + e * 1024;
        int rz = f >> 5;
        int kz = f & 31;
        h[kz * 64 + rz] = z[(row0 + rz) * 32 + kz];
    }
    __syncthreads();

    float acc[16];

    #pragma unroll
    for (int j = 0; j < 16; j++) acc[j] = b1[c0 + j];
    #pragma unroll 8
    for (int k = 0; k < 32; k++) {
        float hv = h[k * 64 + r];
        const float* Wr = W1 + k * 256 + c0;
        #pragma unroll
        for (int j = 0; j < 16; j++) acc[j] = fmaf(hv, Wr[j], acc[j]);
    }
    __syncthreads();
    #pragma unroll
    for (int j = 0; j < 16; j++) h[(c0 + j) * 64 + r] = selu_f(acc[j]);
    __syncthreads();

    for (int layer = 0; layer < 3; layer++) {
        const float* W = (layer == 0) ? W2 : (layer == 1) ? W3 : W4;
        const float* b = (layer == 0) ? b2 : (layer == 1) ? b3 : b4;
        #pragma unroll
        for (int j = 0; j < 16; j++) acc[j] = b[c0 + j];
        #pragma unroll 4
        for (int k = 0; k < 256; k++) {
            float hv = h[k * 64 + r];
            const float* Wr = W + k * 256 + c0;
            #pragma unroll
            for (int j = 0; j < 16; j++) acc[j] = fmaf(hv, Wr[j], acc[j]);
        }
        __syncthreads();
        #pragma unroll
        for (int j = 0; j < 16; j++) h[(c0 + j) * 64 + r] = selu_f(acc[j]);
        __syncthreads();
    }

    float p0 = 0.f, p1 = 0.f;
    #pragma unroll
    for (int kk = 0; kk < 16; kk++) {
        int k = c0 + kk;
        float hv = h[k * 64 + r];
        p0 = fmaf(hv, W5[k * 2 + 0], p0);
        p1 = fmaf(hv, W5[k * 2 + 1], p1);
    }
    __syncthreads();
    h[(0 * 16 + w) * 64 + r] = p0;
    h[(1 * 16 + w) * 64 + r] = p1;
    __syncthreads();
    if (t < 128) {
        int d  = t >> 6;
        int rr = t & 63;
        float sum = b5[d];
        #pragma unroll
        for (int ss = 0; ss < 16; ss++) sum += h[(d * 16 + ss) * 64 + rr];
        gen[(row0 + rr) * 2 + d] = sum;
    }
}

// ---------------------------------------------------------------------------
// Kernel B: SINGLE-PASS softmin-distance energy, fp32 in/out.
// Issue-bound at ~44 cy per wave64 distance-group (93% VALUBusy): 6 VALU +
// v_sqrt + v_exp per pair is the instruction floor for this math.
// ---------------------------------------------------------------------------
__global__ __launch_bounds__(512) void energy_kernel(
    const float* __restrict__ gen,
    const float* __restrict__ pos,
    float* __restrict__ out)
{
    __shared__ float4 sp[512];   // 1024 pos points
    __shared__ float4 sg[512];   // 1024 gen points

    const int t  = threadIdx.x;
    const int s  = t & 31;       // lane within row-group
    const int rl = t >> 5;       // 0..15 row within block
    const int i  = blockIdx.x * 16 + rl;
    const int diagBase = ((blockIdx.x * 16) >> 10) << 10;   // block-uniform

    const float2 q = ((const float2*)gen)[i];

    const float cL2 = 28.853900817779268f;   // 1/(T*ln2) = 20*log2(e)
    const float Tl2 = 0.034657359027997264f; // T*ln2
    const float cB  = 57.707801635558536f;   // cL2 * B, B = 2.0

    float p0 = 0.f, p1 = 0.f, n0 = 0.f, n1 = 0.f;

    for (int base = 0; base < N_PTS; base += 1024) {
        __syncthreads();
        sp[t] = ((const float4*)pos)[base / 2 + t];
        sg[t] = ((const float4*)gen)[base / 2 + t];
        __syncthreads();
        if (base == diagBase) {
            #pragma unroll 4
            for (int u = 0; u < 16; u++) {
                int j = base + 2 * (s + 32 * u);
                float4 pp = sp[s + 32 * u];
                float4 gg = sg[s + 32 * u];
                float dx = q.x - pp.x, dy = q.y - pp.y;
                float d  = fast_sqrtf(fmaf(dx, dx, dy * dy));
                p0 += fast_exp2f(fmaf(-cL2, d, cB));
                dx = q.x - pp.z; dy = q.y - pp.w;
                d  = fast_sqrtf(fmaf(dx, dx, dy * dy));
                p1 += fast_exp2f(fmaf(-cL2, d, cB));
                dx = q.x - gg.x; dy = q.y - gg.y;
                d  = fast_sqrtf(fmaf(dx, dx, dy * dy));
                float e0 = fast_exp2f(fmaf(-cL2, d, cB));
                n0 += (j == i) ? 0.f : e0;
                dx = q.x - gg.z; dy = q.y - gg.w;
                d  = fast_sqrtf(fmaf(dx, dx, dy * dy));
                float e1 = fast_exp2f(fmaf(-cL2, d, cB));
                n1 += (j + 1 == i) ? 0.f : e1;
            }
        } else {
            #pragma unroll 4
            for (int u = 0; u < 16; u++) {
                float4 pp = sp[s + 32 * u];
                float4 gg = sg[s + 32 * u];
                float dx = q.x - pp.x, dy = q.y - pp.y;
                float d  = fast_sqrtf(fmaf(dx, dx, dy * dy));
                p0 += fast_exp2f(fmaf(-cL2, d, cB));
                dx = q.x - pp.z; dy = q.y - pp.w;
                d  = fast_sqrtf(fmaf(dx, dx, dy * dy));
                p1 += fast_exp2f(fmaf(-cL2, d, cB));
                dx = q.x - gg.x; dy = q.y - gg.y;
                d  = fast_sqrtf(fmaf(dx, dx, dy * dy));
                n0 += fast_exp2f(fmaf(-cL2, d, cB));
                dx = q.x - gg.z; dy = q.y - gg.w;
                d  = fast_sqrtf(fmaf(dx, dx, dy * dy));
                n1 += fast_exp2f(fmaf(-cL2, d, cB));
            }
        }
    }

    float sump = p0 + p1;
    float sumn = n0 + n1;
    #pragma unroll
    for (int m = 1; m < 32; m <<= 1) {
        sump += __shfl_xor(sump, m, 32);
        sumn += __shfl_xor(sumn, m, 32);
    }

    if (s == 0) {
        out[i] = Tl2 * (fast_log2f(sumn) - fast_log2f(sump));
    }
}

// ---------------------------------------------------------------------------
extern "C" void kernel_launch(void* const* d_in, const int* in_sizes, int n_in,
                              void* d_out, int out_size, void* d_ws, size_t ws_size,
                              hipStream_t stream) {
    const float* pos = (const float*)d_in[0];
    const float* z   = (const float*)d_in[1];
    const float* W1  = (const float*)d_in[2];
    const float* b1  = (const float*)d_in[3];
    const float* W2  = (const float*)d_in[4];
    const float* b2  = (const float*)d_in[5];
    const float* W3  = (const float*)d_in[6];
    const float* b3  = (const float*)d_in[7];
    const float* W4  = (const float*)d_in[8];
    const float* b4  = (const float*)d_in[9];
    const float* W5  = (const float*)d_in[10];
    const float* b5  = (const float*)d_in[11];

    float* gen = (float*)d_ws;                               // 16384 x 2 fp32
    unsigned short* pk = (unsigned short*)((char*)d_ws + 131072);
    const size_t WS_NEEDED = 131072 + (size_t)409600 * 2;    // gen + packed W

    if (ws_size >= WS_NEEDED) {
        pack_kernel<<<800, 256, 0, stream>>>(W1, W2, W3, W4, pk);
        mlp_mfma_kernel<<<N_PTS / 32, 512, 0, stream>>>(z, pk, b1, b2, b3, b4,
                                                        W5, b5, gen);
    } else {
        mlp_kernel<<<N_PTS / 64, 1024, 0, stream>>>(z, W1, b1, W2, b2, W3, b3,
                                                    W4, b4, W5, b5, gen);
    }
    energy_kernel<<<N_PTS / 16, 512, 0, stream>>>(gen, pos, (float*)d_out);
}